// Round 1
// baseline (1455.568 us; speedup 1.0000x reference)
//
#include <hip/hip_runtime.h>

// ---------------------------------------------------------------------------
// AttentionLayer: q=XWq+bq, k=XWk+bk, v=XWv+bv; S=qk^T (NO 1/sqrt(d) scale);
// P=softmax(S); out=PV.   B=4, L=4096, D=768, fp32 in/out.
//
// Precision strategy: hi/lo _Float16 split (Markidis) for X,W,Q,K so logits
// are accurate to ~1e-3 (softmax here is near-one-hot with std~28 logits, so
// single-half logits would blow the 0.114 absmax budget). P,V in plain f16.
// All matmuls on mfma_f32_16x16x32_f16.
// ---------------------------------------------------------------------------

typedef _Float16 f16;
typedef _Float16 f16x8 __attribute__((ext_vector_type(8)));
typedef _Float16 f16x4 __attribute__((ext_vector_type(4)));
typedef float f32x4 __attribute__((ext_vector_type(4)));

#define NB 4
#define NL 4096
#define ND 768
#define NM (NB * NL)  // 16384 rows

__device__ __forceinline__ void split_f16(float v, f16& h, f16& l) {
    h = (f16)v;
    l = (f16)(v - (float)h);
}

// ---- convert hidden_states -> Xh, Xl (hi/lo f16), same [M][D] layout ------
__global__ __launch_bounds__(256) void k_convert_x(
    const float* __restrict__ x, f16* __restrict__ xh, f16* __restrict__ xl) {
    int i = blockIdx.x * 256 + threadIdx.x;       // group of 4 elems
    float4 v = ((const float4*)x)[i];
    float vv[4] = {v.x, v.y, v.z, v.w};
    f16x4 hv, lv;
    for (int j = 0; j < 4; ++j) {
        f16 h, l; split_f16(vv[j], h, l);
        hv[j] = h; lv[j] = l;
    }
    ((f16x4*)xh)[i] = hv;
    ((f16x4*)xl)[i] = lv;
}

// ---- transpose W [k][n] -> Wt [n][k] as hi/lo f16 (3 matrices, z picks) ---
__global__ __launch_bounds__(256) void k_convert_w(
    const float* __restrict__ Wq, const float* __restrict__ Wk,
    const float* __restrict__ Wv, f16* __restrict__ wth, f16* __restrict__ wtl) {
    __shared__ float tile[32][33];
    const float* W = blockIdx.z == 0 ? Wq : (blockIdx.z == 1 ? Wk : Wv);
    f16* th = wth + blockIdx.z * ND * ND;
    f16* tl = wtl + blockIdx.z * ND * ND;
    const int k0 = blockIdx.x * 32, n0 = blockIdx.y * 32;
    const int tx = threadIdx.x & 31, ty = threadIdx.x >> 5;  // ty 0..7
    for (int r = 0; r < 4; ++r)
        tile[r * 8 + ty][tx] = W[(k0 + r * 8 + ty) * ND + n0 + tx];
    __syncthreads();
    for (int r = 0; r < 4; ++r) {
        float v = tile[tx][r * 8 + ty];
        int n = n0 + r * 8 + ty, k = k0 + tx;
        f16 h, l; split_f16(v, h, l);
        th[n * ND + k] = h;
        tl[n * ND + k] = l;
    }
}

// ---- projection GEMM: C[M,N] = X[M,K] * W[K,N] + bias, hi/lo MFMA ---------
// z=0 -> Qh/Ql, z=1 -> Kh/Kl, z=2 -> Vt (transposed [b][d][pos], hi only)
// 128x128 tile, 4 waves in 2x2, each wave 64x64 = 4x4 frags of 16x16.
__global__ __launch_bounds__(256, 2) void k_proj(
    const f16* __restrict__ xh, const f16* __restrict__ xl,
    const f16* __restrict__ wth, const f16* __restrict__ wtl,
    const float* __restrict__ bq, const float* __restrict__ bk,
    const float* __restrict__ bv,
    f16* __restrict__ qh, f16* __restrict__ ql,
    f16* __restrict__ kh, f16* __restrict__ kl, f16* __restrict__ vt) {
    const int z = blockIdx.z;
    const f16* wh = wth + z * ND * ND;
    const f16* wl = wtl + z * ND * ND;
    const float* bias = z == 0 ? bq : (z == 1 ? bk : bv);
    const int m0 = blockIdx.x * 128, n0 = blockIdx.y * 128;

    // LDS: rows padded to 40 f16 (80B stride -> only 2-way bank aliasing=free)
    __shared__ f16 Ah[128 * 40], Al[128 * 40], Bh[128 * 40], Bl[128 * 40];

    const int t = threadIdx.x;
    const int lane = t & 63, quad = lane >> 4, l16 = lane & 15;
    const int wave = t >> 6, wm = wave >> 1, wn = wave & 1;

    f32x4 acc[4][4] = {};

    for (int kt = 0; kt < 24; ++kt) {
        const int k0 = kt * 32;
        __syncthreads();
        // stage 128x32 tiles (hi+lo of A and B) via 16B chunks
        for (int i = 0; i < 2; ++i) {
            int c = i * 256 + t;
            int row = c >> 2, kc = (c & 3) * 8;
            *(uint4*)&Ah[row * 40 + kc] = *(const uint4*)&xh[(m0 + row) * ND + k0 + kc];
            *(uint4*)&Al[row * 40 + kc] = *(const uint4*)&xl[(m0 + row) * ND + k0 + kc];
            *(uint4*)&Bh[row * 40 + kc] = *(const uint4*)&wh[(n0 + row) * ND + k0 + kc];
            *(uint4*)&Bl[row * 40 + kc] = *(const uint4*)&wl[(n0 + row) * ND + k0 + kc];
        }
        __syncthreads();
        f16x8 ah[4], al[4], bh[4], bl[4];
#pragma unroll
        for (int f = 0; f < 4; ++f) {
            int m = wm * 64 + f * 16 + l16;
            ah[f] = *(const f16x8*)&Ah[m * 40 + quad * 8];
            al[f] = *(const f16x8*)&Al[m * 40 + quad * 8];
            int n = wn * 64 + f * 16 + l16;
            bh[f] = *(const f16x8*)&Bh[n * 40 + quad * 8];
            bl[f] = *(const f16x8*)&Bl[n * 40 + quad * 8];
        }
#pragma unroll
        for (int fm = 0; fm < 4; ++fm)
#pragma unroll
            for (int fn = 0; fn < 4; ++fn) {
                f32x4 c = acc[fm][fn];
                c = __builtin_amdgcn_mfma_f32_16x16x32_f16(al[fm], bh[fn], c, 0, 0, 0);
                c = __builtin_amdgcn_mfma_f32_16x16x32_f16(ah[fm], bl[fn], c, 0, 0, 0);
                c = __builtin_amdgcn_mfma_f32_16x16x32_f16(ah[fm], bh[fn], c, 0, 0, 0);
                acc[fm][fn] = c;
            }
    }
    // epilogue: C/D layout col=lane&15, row=quad*4+reg  [verified m89/m91]
#pragma unroll
    for (int fm = 0; fm < 4; ++fm)
#pragma unroll
        for (int fn = 0; fn < 4; ++fn) {
            int col = n0 + wn * 64 + fn * 16 + l16;
            float bv_ = bias[col];
#pragma unroll
            for (int r = 0; r < 4; ++r) {
                int row = m0 + wm * 64 + fm * 16 + quad * 4 + r;
                float v = acc[fm][fn][r] + bv_;
                f16 h, l; split_f16(v, h, l);
                if (z == 0) { qh[row * ND + col] = h; ql[row * ND + col] = l; }
                else if (z == 1) { kh[row * ND + col] = h; kl[row * ND + col] = l; }
                else {
                    int b = row >> 12, pos = row & 4095;
                    vt[(b * ND + col) * NL + pos] = h;  // V^T for PV b_frags
                }
            }
        }
}

// ---- flash attention: Q-tile=32 rows/block, 4 waves split D into 192-chunks
// S partial per wave over its d-chunk -> LDS reduce -> online softmax -> PV.
__global__ __launch_bounds__(256, 2) void k_attn(
    const f16* __restrict__ qh, const f16* __restrict__ ql,
    const f16* __restrict__ kh, const f16* __restrict__ kl,
    const f16* __restrict__ vt, float* __restrict__ out) {
    const int qt = blockIdx.x, b = blockIdx.y;
    const int q0 = qt * 32;
    const int t = threadIdx.x, w = t >> 6, lane = t & 63;
    const int quad = lane >> 4, l16 = lane & 15;
    const int dw = w * 192;  // this wave's D-chunk for PV/O

    __shared__ float Sbuf[4][32][33];  // per-wave partial S (padded)
    __shared__ f16 Pbuf[32 * 40];      // P tile, row stride 40
    __shared__ float mstate[32], lstate[32], abuf[32];

    if (t < 32) { mstate[t] = -1e30f; lstate[t] = 0.f; }
    f32x4 oacc[2][12] = {};  // O acc: 2 row-frags x 12 col-frags (192 cols)
    __syncthreads();

    for (int kt = 0; kt < 128; ++kt) {
        const int p0 = kt * 32;
        // ---- S partial = Q[q0:q0+32, dw:dw+192] * K^T over this d-chunk ----
        f32x4 sacc[2][2] = {};
#pragma unroll
        for (int dk = 0; dk < 6; ++dk) {
            const int d = dw + dk * 32 + quad * 8;
            f16x8 aH[2], aL[2], bH[2], bL[2];
#pragma unroll
            for (int f = 0; f < 2; ++f) {
                const int qrow = (b * NL + q0 + f * 16 + l16) * ND + d;
                aH[f] = *(const f16x8*)&qh[qrow];
                aL[f] = *(const f16x8*)&ql[qrow];
                const int krow = (b * NL + p0 + f * 16 + l16) * ND + d;
                bH[f] = *(const f16x8*)&kh[krow];
                bL[f] = *(const f16x8*)&kl[krow];
            }
#pragma unroll
            for (int fm = 0; fm < 2; ++fm)
#pragma unroll
                for (int fn = 0; fn < 2; ++fn) {
                    f32x4 c = sacc[fm][fn];
                    c = __builtin_amdgcn_mfma_f32_16x16x32_f16(aL[fm], bH[fn], c, 0, 0, 0);
                    c = __builtin_amdgcn_mfma_f32_16x16x32_f16(aH[fm], bL[fn], c, 0, 0, 0);
                    c = __builtin_amdgcn_mfma_f32_16x16x32_f16(aH[fm], bH[fn], c, 0, 0, 0);
                    sacc[fm][fn] = c;
                }
        }
#pragma unroll
        for (int fm = 0; fm < 2; ++fm)
#pragma unroll
            for (int fn = 0; fn < 2; ++fn)
#pragma unroll
                for (int r = 0; r < 4; ++r)
                    Sbuf[w][fm * 16 + quad * 4 + r][fn * 16 + l16] = sacc[fm][fn][r];
        __syncthreads();

        // ---- online softmax: wave w owns rows 8w..8w+7 (8 lanes per row) ----
        {
            const int r = w * 8 + (lane >> 3);
            const int c0 = (lane & 7) * 4;
            float s[4];
#pragma unroll
            for (int c = 0; c < 4; ++c)
                s[c] = Sbuf[0][r][c0 + c] + Sbuf[1][r][c0 + c] +
                       Sbuf[2][r][c0 + c] + Sbuf[3][r][c0 + c];
            float mx = fmaxf(fmaxf(s[0], s[1]), fmaxf(s[2], s[3]));
            for (int off = 1; off < 8; off <<= 1) mx = fmaxf(mx, __shfl_xor(mx, off, 64));
            float m_old = mstate[r];
            float m_new = fmaxf(m_old, mx);
            float p[4], psum = 0.f;
#pragma unroll
            for (int c = 0; c < 4; ++c) { p[c] = __expf(s[c] - m_new); psum += p[c]; }
            for (int off = 1; off < 8; off <<= 1) psum += __shfl_xor(psum, off, 64);
            float alpha = __expf(m_old - m_new);
            if ((lane & 7) == 0) {
                mstate[r] = m_new;
                lstate[r] = alpha * lstate[r] + psum;
                abuf[r] = alpha;
            }
#pragma unroll
            for (int c = 0; c < 4; ++c) Pbuf[r * 40 + c0 + c] = (f16)p[c];
        }
        __syncthreads();

        // ---- rescale O by alpha, then O += P * V over this d-chunk ----
        float av[2][4];
#pragma unroll
        for (int fm = 0; fm < 2; ++fm)
#pragma unroll
            for (int r = 0; r < 4; ++r) av[fm][r] = abuf[fm * 16 + quad * 4 + r];
#pragma unroll
        for (int fm = 0; fm < 2; ++fm)
#pragma unroll
            for (int fn = 0; fn < 12; ++fn)
#pragma unroll
                for (int r = 0; r < 4; ++r) oacc[fm][fn][r] *= av[fm][r];

        f16x8 pa[2];
#pragma unroll
        for (int fm = 0; fm < 2; ++fm)
            pa[fm] = *(const f16x8*)&Pbuf[(fm * 16 + l16) * 40 + quad * 8];
#pragma unroll
        for (int fn = 0; fn < 12; ++fn) {
            const int dcol = dw + fn * 16 + l16;
            f16x8 vb = *(const f16x8*)&vt[(b * ND + dcol) * NL + p0 + quad * 8];
#pragma unroll
            for (int fm = 0; fm < 2; ++fm)
                oacc[fm][fn] = __builtin_amdgcn_mfma_f32_16x16x32_f16(pa[fm], vb, oacc[fm][fn], 0, 0, 0);
        }
        __syncthreads();  // Sbuf/Pbuf/abuf reused next tile
    }

    // ---- epilogue: out = O / l ----
    float linv[2][4];
#pragma unroll
    for (int fm = 0; fm < 2; ++fm)
#pragma unroll
        for (int r = 0; r < 4; ++r) linv[fm][r] = 1.f / lstate[fm * 16 + quad * 4 + r];
#pragma unroll
    for (int fm = 0; fm < 2; ++fm)
#pragma unroll
        for (int fn = 0; fn < 12; ++fn) {
            int col = dw + fn * 16 + l16;
#pragma unroll
            for (int r = 0; r < 4; ++r) {
                int row = b * NL + q0 + fm * 16 + quad * 4 + r;
                out[row * ND + col] = oacc[fm][fn][r] * linv[fm][r];
            }
        }
}

extern "C" void kernel_launch(void* const* d_in, const int* in_sizes, int n_in,
                              void* d_out, int out_size, void* d_ws, size_t ws_size,
                              hipStream_t stream) {
    const float* hs = (const float*)d_in[0];
    const float* Wq = (const float*)d_in[1];
    const float* bq = (const float*)d_in[2];
    const float* Wk = (const float*)d_in[3];
    const float* bk = (const float*)d_in[4];
    const float* Wv = (const float*)d_in[5];
    const float* bv = (const float*)d_in[6];
    float* out = (float*)d_out;

    char* ws = (char*)d_ws;
    size_t off = 0;
    auto alloc = [&](size_t bytes) {
        void* p = ws + off;
        off += (bytes + 255) & ~(size_t)255;
        return p;
    };
    const size_t MD = (size_t)NM * ND;  // 12,582,912
    f16* Xh = (f16*)alloc(MD * 2);
    f16* Xl = (f16*)alloc(MD * 2);
    f16* Wth = (f16*)alloc((size_t)3 * ND * ND * 2);
    f16* Wtl = (f16*)alloc((size_t)3 * ND * ND * 2);
    f16* Qh = (f16*)alloc(MD * 2);
    f16* Ql = (f16*)alloc(MD * 2);
    f16* Kh = (f16*)alloc(MD * 2);
    f16* Kl = (f16*)alloc(MD * 2);
    f16* Vt = (f16*)alloc(MD * 2);
    (void)ws_size; (void)in_sizes; (void)n_in; (void)out_size;

    k_convert_x<<<dim3(MD / 1024), 256, 0, stream>>>(hs, Xh, Xl);
    k_convert_w<<<dim3(24, 24, 3), 256, 0, stream>>>(Wq, Wk, Wv, Wth, Wtl);
    k_proj<<<dim3(NM / 128, ND / 128, 3), 256, 0, stream>>>(
        Xh, Xl, Wth, Wtl, bq, bk, bv, Qh, Ql, Kh, Kl, Vt);
    k_attn<<<dim3(NL / 32, NB), 256, 0, stream>>>(Qh, Ql, Kh, Kl, Vt, out);
}